// Round 1
// baseline (431.155 us; speedup 1.0000x reference)
//
#include <hip/hip_runtime.h>
#include <math.h>

#define V_NUM 6890
#define NJ 24
#define KTOT 217   // 10 betas + 207 pose_map
#define M_DIM (V_NUM * 3)  // 20670

__constant__ int c_parents[NJ] = {-1,0,0,0,1,2,3,4,5,6,7,8,9,9,9,12,13,14,16,17,18,19,20,21};

// ---------------- Kernel A: fold J_regressor into shapedirs/template ----------------
// JS[j][cc][ss] (24*3*10), Jt[j][cc] (24*3)
__global__ __launch_bounds__(256) void k_regress(
    const float* __restrict__ JR, const float* __restrict__ SD,
    const float* __restrict__ VT, float* __restrict__ JS, float* __restrict__ Jt) {
  int j = blockIdx.x;
  int tid = threadIdx.x;
  float part[33];
#pragma unroll
  for (int q = 0; q < 33; q++) part[q] = 0.f;
  for (int v = tid; v < V_NUM; v += 256) {
    float jr = JR[j * V_NUM + v];
#pragma unroll
    for (int cc = 0; cc < 3; cc++) {
      part[30 + cc] += jr * VT[v * 3 + cc];
#pragma unroll
      for (int ss = 0; ss < 10; ss++)
        part[cc * 10 + ss] += jr * SD[(v * 3 + cc) * 10 + ss];
    }
  }
  __shared__ float sm[33][4];
  int lane = tid & 63, wid = tid >> 6;
#pragma unroll
  for (int q = 0; q < 33; q++) {
    float x = part[q];
    for (int off = 32; off > 0; off >>= 1) x += __shfl_down(x, off);
    if (lane == 0) sm[q][wid] = x;
  }
  __syncthreads();
  if (tid < 33) {
    float s = sm[tid][0] + sm[tid][1] + sm[tid][2] + sm[tid][3];
    if (tid < 30) JS[j * 30 + tid] = s;
    else Jt[j * 3 + (tid - 30)] = s;
  }
}

// ---------------- Kernel B: per-batch rodrigues + joints + kinematic chain ----------------
// Writes: Kc [KTOT][B] (betas rows 0..9, posemap rows 10..216), Grel [B][24][12],
//         outG [B][24][16], outJtr [B][24][3]
__global__ __launch_bounds__(64) void k_batch(
    const float* __restrict__ pose, const float* __restrict__ betas,
    const float* __restrict__ trans, const float* __restrict__ JS,
    const float* __restrict__ Jt, float* __restrict__ Kc,
    float* __restrict__ Grel, float* __restrict__ outG,
    float* __restrict__ outJtr, int B) {
  int b = blockIdx.x;
  int lane = threadIdx.x;
  __shared__ float rotS[NJ][9];
  __shared__ float jS[NJ * 3];
  __shared__ float Gs[NJ][12];   // rows p=0..2 of [R|t]
  __shared__ float GrS[NJ][12];  // G_rel top 3 rows

  if (lane < NJ) {
    float rx = pose[b * 72 + lane * 3 + 0];
    float ry = pose[b * 72 + lane * 3 + 1];
    float rz = pose[b * 72 + lane * 3 + 2];
    float a2 = rx * rx + ry * ry + rz * rz + 1e-16f;
    float ang = sqrtf(a2);
    float inv = 1.f / ang;
    float ux = rx * inv, uy = ry * inv, uz = rz * inv;
    float c = cosf(ang), s = sinf(ang), ic = 1.f - c;
    float R[9];
    R[0] = c + ic * ux * ux;      R[1] = ic * ux * uy - s * uz; R[2] = ic * ux * uz + s * uy;
    R[3] = ic * uy * ux + s * uz; R[4] = c + ic * uy * uy;      R[5] = ic * uy * uz - s * ux;
    R[6] = ic * uz * ux - s * uy; R[7] = ic * uz * uy + s * ux; R[8] = c + ic * uz * uz;
#pragma unroll
    for (int k = 0; k < 9; k++) rotS[lane][k] = R[k];
    if (lane > 0) {
#pragma unroll
      for (int k = 0; k < 9; k++) {
        float iden = (k == 0 || k == 4 || k == 8) ? 1.f : 0.f;
        Kc[(size_t)(10 + (lane - 1) * 9 + k) * B + b] = R[k] - iden;
      }
    }
  }
  if (lane < 10) Kc[(size_t)lane * B + b] = betas[b * 10 + lane];

  __syncthreads();
  // joints: 72 components
  for (int idx = lane; idx < 72; idx += 64) {
    float s = Jt[idx];
#pragma unroll
    for (int ss = 0; ss < 10; ss++) s += JS[idx * 10 + ss] * betas[b * 10 + ss];
    jS[idx] = s;
  }
  __syncthreads();

  if (lane == 0) {
    // root
#pragma unroll
    for (int p = 0; p < 3; p++) {
      Gs[0][p * 4 + 0] = rotS[0][p * 3 + 0];
      Gs[0][p * 4 + 1] = rotS[0][p * 3 + 1];
      Gs[0][p * 4 + 2] = rotS[0][p * 3 + 2];
      Gs[0][p * 4 + 3] = jS[p];
    }
    for (int i = 1; i < NJ; i++) {
      int par = c_parents[i];
      float t0 = jS[i * 3 + 0] - jS[par * 3 + 0];
      float t1 = jS[i * 3 + 1] - jS[par * 3 + 1];
      float t2 = jS[i * 3 + 2] - jS[par * 3 + 2];
#pragma unroll
      for (int p = 0; p < 3; p++) {
        float rp0 = Gs[par][p * 4 + 0], rp1 = Gs[par][p * 4 + 1], rp2 = Gs[par][p * 4 + 2];
#pragma unroll
        for (int q = 0; q < 3; q++) {
          Gs[i][p * 4 + q] = rp0 * rotS[i][0 * 3 + q] + rp1 * rotS[i][1 * 3 + q] + rp2 * rotS[i][2 * 3 + q];
        }
        Gs[i][p * 4 + 3] = rp0 * t0 + rp1 * t1 + rp2 * t2 + Gs[par][p * 4 + 3];
      }
    }
    // G_rel
    for (int i = 0; i < NJ; i++) {
      float jx = jS[i * 3 + 0], jy = jS[i * 3 + 1], jz = jS[i * 3 + 2];
#pragma unroll
      for (int p = 0; p < 3; p++) {
        float g0 = Gs[i][p * 4 + 0], g1 = Gs[i][p * 4 + 1], g2 = Gs[i][p * 4 + 2];
        GrS[i][p * 4 + 0] = g0;
        GrS[i][p * 4 + 1] = g1;
        GrS[i][p * 4 + 2] = g2;
        GrS[i][p * 4 + 3] = Gs[i][p * 4 + 3] - (g0 * jx + g1 * jy + g2 * jz);
      }
    }
  }
  __syncthreads();

  // outputs
  for (int idx = lane; idx < NJ * 16; idx += 64) {
    int jj = idx >> 4, rc = idx & 15, p = rc >> 2, q = rc & 3;
    float val = (p < 3) ? Gs[jj][p * 4 + q] : ((q == 3) ? 1.f : 0.f);
    outG[(size_t)b * NJ * 16 + idx] = val;
  }
  for (int idx = lane; idx < NJ * 3; idx += 64) {
    int jj = idx / 3, p = idx % 3;
    outJtr[(size_t)b * NJ * 3 + idx] = Gs[jj][p * 4 + 3] + trans[b * 3 + p];
  }
  for (int idx = lane; idx < NJ * 12; idx += 64) {
    Grel[(size_t)b * NJ * 12 + idx] = GrS[idx / 12][idx % 12];
  }
}

// ---------------- Kernel C: big GEMM  naked[m,b] = vt[m] + sum_k A[m,k]*Kc[k,b] ----------------
// A[m,k]: k<10 -> SD[m*10+k], else PD[m*207+k-10].  Output to v_posed and naked regions.
__global__ __launch_bounds__(256) void k_pose_gemm(
    const float* __restrict__ SD, const float* __restrict__ PD,
    const float* __restrict__ VT, const float* __restrict__ Kc,
    float* __restrict__ outVP, float* __restrict__ outNK, int B) {
  __shared__ float As[8][128];
  __shared__ float Bs[8][128];
  int bm0 = blockIdx.x * 128;
  int bn0 = blockIdx.y * 128;
  int tid = threadIdx.x;
  int tm = tid & 15, tb = tid >> 4;
  float acc[8][8];
#pragma unroll
  for (int i = 0; i < 8; i++)
#pragma unroll
    for (int j = 0; j < 8; j++) acc[i][j] = 0.f;

  for (int k0 = 0; k0 < KTOT; k0 += 8) {
    // load A tile: 128 rows x 8 cols
    {
      int mm = tid >> 1;
      int kb = (tid & 1) * 4;
      int m = bm0 + mm;
#pragma unroll
      for (int l = 0; l < 4; l++) {
        int col = k0 + kb + l;
        float v = 0.f;
        if (m < M_DIM && col < KTOT)
          v = (col < 10) ? SD[(size_t)m * 10 + col] : PD[(size_t)m * 207 + (col - 10)];
        As[kb + l][mm] = v;
      }
      int bb = tid & 127;
#pragma unroll
      for (int l = 0; l < 4; l++) {
        int kk = (tid >> 7) + l * 2;
        int col = k0 + kk;
        Bs[kk][bb] = (col < KTOT) ? Kc[(size_t)col * B + bn0 + bb] : 0.f;
      }
    }
    __syncthreads();
#pragma unroll
    for (int kk = 0; kk < 8; kk++) {
      float a[8], bv[8];
#pragma unroll
      for (int i = 0; i < 8; i++) a[i] = As[kk][tm * 8 + i];
#pragma unroll
      for (int i = 0; i < 8; i++) bv[i] = Bs[kk][tb * 8 + i];
#pragma unroll
      for (int i = 0; i < 8; i++)
#pragma unroll
        for (int j = 0; j < 8; j++) acc[i][j] += bv[i] * a[j];
    }
    __syncthreads();
  }
  // epilogue: acc[i=b][j=m]
#pragma unroll
  for (int i = 0; i < 8; i++) {
    int b = bn0 + tb * 8 + i;
    if (b >= B) continue;
    size_t base = (size_t)b * M_DIM;
#pragma unroll
    for (int j = 0; j < 8; j++) {
      int m = bm0 + tm * 8 + j;
      if (m < M_DIM) {
        float vout = acc[i][j] + VT[m];
        outVP[base + m] = vout;
        outNK[base + m] = vout;
      }
    }
  }
}

// ---------------- Kernel D: skinning ----------------
__global__ __launch_bounds__(256) void k_skin(
    const float* __restrict__ NK, const float* __restrict__ W,
    const float* __restrict__ Grel, const float* __restrict__ trans,
    float* __restrict__ outVerts, int B) {
  int v = blockIdx.x * 256 + threadIdx.x;
  int b0 = blockIdx.y * 8;
  if (v >= V_NUM) return;
  float w[NJ];
#pragma unroll
  for (int j = 0; j < NJ; j++) w[j] = W[(size_t)v * NJ + j];
#pragma unroll
  for (int bb = 0; bb < 8; bb++) {
    int b = b0 + bb;
    size_t base = (size_t)b * M_DIM + (size_t)v * 3;
    float x0 = NK[base + 0], x1 = NK[base + 1], x2 = NK[base + 2];
    float a0 = 0.f, a1 = 0.f, a2 = 0.f;
    const float* g = Grel + (size_t)b * NJ * 12;
#pragma unroll
    for (int j = 0; j < NJ; j++) {
      const float* gj = g + j * 12;
      float wj = w[j];
      a0 += wj * (gj[0] * x0 + gj[1] * x1 + gj[2] * x2 + gj[3]);
      a1 += wj * (gj[4] * x0 + gj[5] * x1 + gj[6] * x2 + gj[7]);
      a2 += wj * (gj[8] * x0 + gj[9] * x1 + gj[10] * x2 + gj[11]);
    }
    outVerts[base + 0] = a0 + trans[b * 3 + 0];
    outVerts[base + 1] = a1 + trans[b * 3 + 1];
    outVerts[base + 2] = a2 + trans[b * 3 + 2];
  }
}

extern "C" void kernel_launch(void* const* d_in, const int* in_sizes, int n_in,
                              void* d_out, int out_size, void* d_ws, size_t ws_size,
                              hipStream_t stream) {
  const float* pose  = (const float*)d_in[0];
  const float* betas = (const float*)d_in[1];
  const float* trans = (const float*)d_in[2];
  const float* vt    = (const float*)d_in[3];
  const float* sd    = (const float*)d_in[4];
  const float* pd    = (const float*)d_in[5];
  const float* jreg  = (const float*)d_in[6];
  const float* wgt   = (const float*)d_in[7];
  int B = in_sizes[0] / 72;

  float* out = (float*)d_out;
  size_t nvb = (size_t)B * M_DIM;
  float* o_verts = out;
  float* o_jtr   = o_verts + nvb;
  float* o_vp    = o_jtr + (size_t)B * NJ * 3;
  float* o_nk    = o_vp + nvb;
  float* o_G     = o_nk + nvb;

  float* ws   = (float*)d_ws;
  float* JS   = ws;                         // 720
  float* Jt   = ws + 720;                   // 72
  float* Kc   = ws + 792;                   // KTOT*B
  float* Grel = Kc + (size_t)KTOT * B;      // B*288

  k_regress<<<24, 256, 0, stream>>>(jreg, sd, vt, JS, Jt);
  k_batch<<<B, 64, 0, stream>>>(pose, betas, trans, JS, Jt, Kc, Grel, o_G, o_jtr, B);
  dim3 gC((M_DIM + 127) / 128, (B + 127) / 128);
  k_pose_gemm<<<gC, 256, 0, stream>>>(sd, pd, vt, Kc, o_vp, o_nk, B);
  dim3 gD((V_NUM + 255) / 256, (B + 7) / 8);
  k_skin<<<gD, 256, 0, stream>>>(o_nk, wgt, Grel, trans, o_verts, B);
}

// Round 2
// 269.279 us; speedup vs baseline: 1.6011x; 1.6011x over previous
//
#include <hip/hip_runtime.h>
#include <math.h>

#define V_NUM 6890
#define NJ 24
#define KTOT 217            // 10 betas + 207 pose_map
#define KP 256              // padded K (multiple of 64)
#define M_DIM (V_NUM * 3)   // 20670
#define MPAD 20736          // 162 * 128

typedef __attribute__((ext_vector_type(8))) short bf16x8;
typedef __attribute__((ext_vector_type(4))) float f32x4;

__constant__ int c_parents[NJ] = {-1,0,0,0,1,2,3,4,5,6,7,8,9,9,9,12,13,14,16,17,18,19,20,21};

__device__ __forceinline__ unsigned short f2bf(float x) {
  union { float f; unsigned int u; } v; v.f = x;
  unsigned int r = v.u + 0x7fffu + ((v.u >> 16) & 1u);
  return (unsigned short)(r >> 16);
}

#define GLOBAL_AS __attribute__((address_space(1)))
#define LDS_AS __attribute__((address_space(3)))
__device__ __forceinline__ void gl_lds16(const void* g, void* l) {
  __builtin_amdgcn_global_load_lds((const GLOBAL_AS unsigned int*)g,
                                   (LDS_AS unsigned int*)l, 16, 0, 0);
}

// ---------------- Kernel A: fold J_regressor into shapedirs/template ----------------
__global__ __launch_bounds__(256) void k_regress(
    const float* __restrict__ JR, const float* __restrict__ SD,
    const float* __restrict__ VT, float* __restrict__ JS, float* __restrict__ Jt) {
  int j = blockIdx.x;
  int tid = threadIdx.x;
  float part[33];
#pragma unroll
  for (int q = 0; q < 33; q++) part[q] = 0.f;
  for (int v = tid; v < V_NUM; v += 256) {
    float jr = JR[j * V_NUM + v];
#pragma unroll
    for (int cc = 0; cc < 3; cc++) {
      part[30 + cc] += jr * VT[v * 3 + cc];
#pragma unroll
      for (int ss = 0; ss < 10; ss++)
        part[cc * 10 + ss] += jr * SD[(v * 3 + cc) * 10 + ss];
    }
  }
  __shared__ float sm[33][4];
  int lane = tid & 63, wid = tid >> 6;
#pragma unroll
  for (int q = 0; q < 33; q++) {
    float x = part[q];
    for (int off = 32; off > 0; off >>= 1) x += __shfl_down(x, off);
    if (lane == 0) sm[q][wid] = x;
  }
  __syncthreads();
  if (tid < 33) {
    float s = sm[tid][0] + sm[tid][1] + sm[tid][2] + sm[tid][3];
    if (tid < 30) JS[j * 30 + tid] = s;
    else Jt[j * 3 + (tid - 30)] = s;
  }
}

// ---------------- Kernel A2: convert A = [shapedirs | posedirs] -> bf16 [MPAD][KP] ----------------
__global__ __launch_bounds__(256) void k_convA(
    const float* __restrict__ SD, const float* __restrict__ PD,
    unsigned short* __restrict__ Abf) {
  int m = blockIdx.x;        // 0..MPAD-1
  int k = threadIdx.x;       // 0..255
  float v = 0.f;
  if (m < M_DIM && k < KTOT)
    v = (k < 10) ? SD[(size_t)m * 10 + k] : PD[(size_t)m * 207 + (k - 10)];
  Abf[(size_t)m * KP + k] = f2bf(v);
}

// ---------------- Kernel B: per-batch rodrigues + joints + kinematic chain ----------------
// Writes: Kcb [B][KP] bf16 (betas 0..9, posemap 10..216, zeros 217..255),
//         Grel [B][24][12] f32, outG [B][24][16], outJtr [B][24][3]
__global__ __launch_bounds__(64) void k_batch(
    const float* __restrict__ pose, const float* __restrict__ betas,
    const float* __restrict__ trans, const float* __restrict__ JS,
    const float* __restrict__ Jt, unsigned short* __restrict__ Kcb,
    float* __restrict__ Grel, float* __restrict__ outG,
    float* __restrict__ outJtr, int B) {
  int b = blockIdx.x;
  int lane = threadIdx.x;
  __shared__ float rotS[NJ][9];
  __shared__ float jS[NJ * 3];
  __shared__ float Gs[NJ][12];
  __shared__ float GrS[NJ][12];

  if (lane < NJ) {
    float rx = pose[b * 72 + lane * 3 + 0];
    float ry = pose[b * 72 + lane * 3 + 1];
    float rz = pose[b * 72 + lane * 3 + 2];
    float a2 = rx * rx + ry * ry + rz * rz + 1e-16f;
    float ang = sqrtf(a2);
    float inv = 1.f / ang;
    float ux = rx * inv, uy = ry * inv, uz = rz * inv;
    float c = cosf(ang), s = sinf(ang), ic = 1.f - c;
    float R[9];
    R[0] = c + ic * ux * ux;      R[1] = ic * ux * uy - s * uz; R[2] = ic * ux * uz + s * uy;
    R[3] = ic * uy * ux + s * uz; R[4] = c + ic * uy * uy;      R[5] = ic * uy * uz - s * ux;
    R[6] = ic * uz * ux - s * uy; R[7] = ic * uz * uy + s * ux; R[8] = c + ic * uz * uz;
#pragma unroll
    for (int k = 0; k < 9; k++) rotS[lane][k] = R[k];
    if (lane > 0) {
#pragma unroll
      for (int k = 0; k < 9; k++) {
        float iden = (k == 0 || k == 4 || k == 8) ? 1.f : 0.f;
        Kcb[(size_t)b * KP + 10 + (lane - 1) * 9 + k] = f2bf(R[k] - iden);
      }
    }
  }
  if (lane < 10) Kcb[(size_t)b * KP + lane] = f2bf(betas[b * 10 + lane]);
  if (lane < KP - KTOT) Kcb[(size_t)b * KP + KTOT + lane] = 0;  // zero pad 217..255

  __syncthreads();
  for (int idx = lane; idx < 72; idx += 64) {
    float s = Jt[idx];
#pragma unroll
    for (int ss = 0; ss < 10; ss++) s += JS[idx * 10 + ss] * betas[b * 10 + ss];
    jS[idx] = s;
  }
  __syncthreads();

  if (lane == 0) {
#pragma unroll
    for (int p = 0; p < 3; p++) {
      Gs[0][p * 4 + 0] = rotS[0][p * 3 + 0];
      Gs[0][p * 4 + 1] = rotS[0][p * 3 + 1];
      Gs[0][p * 4 + 2] = rotS[0][p * 3 + 2];
      Gs[0][p * 4 + 3] = jS[p];
    }
    for (int i = 1; i < NJ; i++) {
      int par = c_parents[i];
      float t0 = jS[i * 3 + 0] - jS[par * 3 + 0];
      float t1 = jS[i * 3 + 1] - jS[par * 3 + 1];
      float t2 = jS[i * 3 + 2] - jS[par * 3 + 2];
#pragma unroll
      for (int p = 0; p < 3; p++) {
        float rp0 = Gs[par][p * 4 + 0], rp1 = Gs[par][p * 4 + 1], rp2 = Gs[par][p * 4 + 2];
#pragma unroll
        for (int q = 0; q < 3; q++) {
          Gs[i][p * 4 + q] = rp0 * rotS[i][0 * 3 + q] + rp1 * rotS[i][1 * 3 + q] + rp2 * rotS[i][2 * 3 + q];
        }
        Gs[i][p * 4 + 3] = rp0 * t0 + rp1 * t1 + rp2 * t2 + Gs[par][p * 4 + 3];
      }
    }
    for (int i = 0; i < NJ; i++) {
      float jx = jS[i * 3 + 0], jy = jS[i * 3 + 1], jz = jS[i * 3 + 2];
#pragma unroll
      for (int p = 0; p < 3; p++) {
        float g0 = Gs[i][p * 4 + 0], g1 = Gs[i][p * 4 + 1], g2 = Gs[i][p * 4 + 2];
        GrS[i][p * 4 + 0] = g0;
        GrS[i][p * 4 + 1] = g1;
        GrS[i][p * 4 + 2] = g2;
        GrS[i][p * 4 + 3] = Gs[i][p * 4 + 3] - (g0 * jx + g1 * jy + g2 * jz);
      }
    }
  }
  __syncthreads();

  for (int idx = lane; idx < NJ * 16; idx += 64) {
    int jj = idx >> 4, rc = idx & 15, p = rc >> 2, q = rc & 3;
    float val = (p < 3) ? Gs[jj][p * 4 + q] : ((q == 3) ? 1.f : 0.f);
    outG[(size_t)b * NJ * 16 + idx] = val;
  }
  for (int idx = lane; idx < NJ * 3; idx += 64) {
    int jj = idx / 3, p = idx % 3;
    outJtr[(size_t)b * NJ * 3 + idx] = Gs[jj][p * 4 + 3] + trans[b * 3 + p];
  }
  for (int idx = lane; idx < NJ * 12; idx += 64) {
    Grel[(size_t)b * NJ * 12 + idx] = GrS[idx / 12][idx % 12];
  }
}

// ---------------- Kernel C: MFMA GEMM  D[b][m] = sum_k Kcb[b][k] * Abf[m][k] + VT[m] ----------------
// Output rows = b (128/tile), cols = m (128/tile). 4 waves (2x2), each 64x64.
// LDS tiles [128 rows][64 k] bf16 = 16KB each, XOR-swizzled: byte ^= (row&7)<<4.
// Staged via global_load_lds with pre-swizzled global source (linear LDS dest).
__global__ __launch_bounds__(256) void k_pose_mfma(
    const unsigned short* __restrict__ Kcb, const unsigned short* __restrict__ Abf,
    const float* __restrict__ VT,
    float* __restrict__ outVP, float* __restrict__ outNK, int B) {
  __shared__ unsigned short At[128 * 64];  // rows = b-local
  __shared__ unsigned short Bt[128 * 64];  // rows = m-local
  const int tid = threadIdx.x;
  const int lane = tid & 63;
  const int w = tid >> 6;
  const int wr = w >> 1, wc = w & 1;
  const int b0 = blockIdx.y * 128;
  const int m0 = blockIdx.x * 128;

  f32x4 acc[4][4];
#pragma unroll
  for (int i = 0; i < 4; i++)
#pragma unroll
    for (int j = 0; j < 4; j++) acc[i][j] = (f32x4){0.f, 0.f, 0.f, 0.f};

  // per-lane linear-L derived source row/offset (same for all kt; kt only shifts k base)
  int Lrow[4], Lkb[4];
#pragma unroll
  for (int i = 0; i < 4; i++) {
    int L = w * 4096 + i * 1024 + lane * 16;     // linear byte within 16KB tile
    int row = L >> 7;                            // 128B per row
    int kb = (L & 127) ^ ((row & 7) << 4);       // inverse swizzle on source
    Lrow[i] = row;
    Lkb[i] = kb >> 1;                            // ushort offset within row (0..63)
  }

  for (int kt = 0; kt < KP / 64; ++kt) {
#pragma unroll
    for (int i = 0; i < 4; i++) {
      const unsigned short* gA = Kcb + (size_t)(b0 + Lrow[i]) * KP + kt * 64 + Lkb[i];
      gl_lds16(gA, (char*)At + w * 4096 + i * 1024);
    }
#pragma unroll
    for (int i = 0; i < 4; i++) {
      const unsigned short* gB = Abf + (size_t)(m0 + Lrow[i]) * KP + kt * 64 + Lkb[i];
      gl_lds16(gB, (char*)Bt + w * 4096 + i * 1024);
    }
    __syncthreads();  // drains vmcnt before barrier

#pragma unroll
    for (int h = 0; h < 2; ++h) {
      bf16x8 af[4], bfr[4];
#pragma unroll
      for (int fi = 0; fi < 4; fi++) {
        int row = wr * 64 + fi * 16 + (lane & 15);
        int byte = (row << 7) + ((h * 64 + ((lane >> 4) << 4)) ^ ((row & 7) << 4));
        af[fi] = *(const bf16x8*)((const char*)At + byte);
      }
#pragma unroll
      for (int fj = 0; fj < 4; fj++) {
        int row = wc * 64 + fj * 16 + (lane & 15);
        int byte = (row << 7) + ((h * 64 + ((lane >> 4) << 4)) ^ ((row & 7) << 4));
        bfr[fj] = *(const bf16x8*)((const char*)Bt + byte);
      }
#pragma unroll
      for (int fi = 0; fi < 4; fi++)
#pragma unroll
        for (int fj = 0; fj < 4; fj++)
          acc[fi][fj] = __builtin_amdgcn_mfma_f32_16x16x32_bf16(af[fi], bfr[fj], acc[fi][fj], 0, 0, 0);
    }
    __syncthreads();
  }

  // epilogue: C/D layout col=lane&15, row=(lane>>4)*4+reg
#pragma unroll
  for (int fj = 0; fj < 4; fj++) {
    int cm = m0 + wc * 64 + fj * 16 + (lane & 15);
    if (cm >= M_DIM) continue;
    float vt = VT[cm];
#pragma unroll
    for (int fi = 0; fi < 4; fi++) {
      int rb = b0 + wr * 64 + fi * 16 + ((lane >> 4) << 2);
#pragma unroll
      for (int r = 0; r < 4; r++) {
        float val = acc[fi][fj][r] + vt;
        size_t o = (size_t)(rb + r) * M_DIM + cm;
        outVP[o] = val;
        outNK[o] = val;
      }
    }
  }
}

// ---------------- Kernel D: skinning ----------------
__global__ __launch_bounds__(256) void k_skin(
    const float* __restrict__ NK, const float* __restrict__ W,
    const float* __restrict__ Grel, const float* __restrict__ trans,
    float* __restrict__ outVerts, int B) {
  __shared__ float gS[8 * 288];
  __shared__ float tS[8 * 3];
  int tid = threadIdx.x;
  int b0 = blockIdx.y * 8;
  for (int i = tid; i < 8 * 288; i += 256) gS[i] = Grel[(size_t)b0 * 288 + i];
  if (tid < 24) tS[tid] = trans[b0 * 3 + tid];
  __syncthreads();
  int v = blockIdx.x * 256 + tid;
  if (v >= V_NUM) return;
  float w[NJ];
  const float4* wp = (const float4*)&W[(size_t)v * NJ];
#pragma unroll
  for (int q = 0; q < 6; q++) {
    float4 t = wp[q];
    w[q * 4 + 0] = t.x; w[q * 4 + 1] = t.y; w[q * 4 + 2] = t.z; w[q * 4 + 3] = t.w;
  }
#pragma unroll
  for (int bb = 0; bb < 8; bb++) {
    int b = b0 + bb;
    size_t base = (size_t)b * M_DIM + (size_t)v * 3;
    float x0 = NK[base + 0], x1 = NK[base + 1], x2 = NK[base + 2];
    float a0 = 0.f, a1 = 0.f, a2 = 0.f;
    const float* g = &gS[bb * 288];
#pragma unroll
    for (int j = 0; j < NJ; j++) {
      const float* gj = g + j * 12;
      float wj = w[j];
      a0 += wj * (gj[0] * x0 + gj[1] * x1 + gj[2] * x2 + gj[3]);
      a1 += wj * (gj[4] * x0 + gj[5] * x1 + gj[6] * x2 + gj[7]);
      a2 += wj * (gj[8] * x0 + gj[9] * x1 + gj[10] * x2 + gj[11]);
    }
    outVerts[base + 0] = a0 + tS[bb * 3 + 0];
    outVerts[base + 1] = a1 + tS[bb * 3 + 1];
    outVerts[base + 2] = a2 + tS[bb * 3 + 2];
  }
}

extern "C" void kernel_launch(void* const* d_in, const int* in_sizes, int n_in,
                              void* d_out, int out_size, void* d_ws, size_t ws_size,
                              hipStream_t stream) {
  const float* pose  = (const float*)d_in[0];
  const float* betas = (const float*)d_in[1];
  const float* trans = (const float*)d_in[2];
  const float* vt    = (const float*)d_in[3];
  const float* sd    = (const float*)d_in[4];
  const float* pd    = (const float*)d_in[5];
  const float* jreg  = (const float*)d_in[6];
  const float* wgt   = (const float*)d_in[7];
  int B = in_sizes[0] / 72;

  float* out = (float*)d_out;
  size_t nvb = (size_t)B * M_DIM;
  float* o_verts = out;
  float* o_jtr   = o_verts + nvb;
  float* o_vp    = o_jtr + (size_t)B * NJ * 3;
  float* o_nk    = o_vp + nvb;
  float* o_G     = o_nk + nvb;

  char* wsb = (char*)d_ws;
  float* JS   = (float*)wsb;                       // 720 f32
  float* Jt   = JS + 720;                          // 72 f32
  float* Grel = Jt + 72;                           // B*288 f32
  size_t off = (720 + 72 + (size_t)B * 288) * 4;   // = 1,182,816 for B=1024 (16-aligned)
  unsigned short* Kcb = (unsigned short*)(wsb + off);            // B*KP bf16
  unsigned short* Abf = (unsigned short*)(wsb + off + (size_t)B * KP * 2);  // MPAD*KP bf16

  k_regress<<<24, 256, 0, stream>>>(jreg, sd, vt, JS, Jt);
  k_convA<<<MPAD, 256, 0, stream>>>(sd, pd, Abf);
  k_batch<<<B, 64, 0, stream>>>(pose, betas, trans, JS, Jt, Kcb, Grel, o_G, o_jtr, B);
  dim3 gC(MPAD / 128, B / 128);
  k_pose_mfma<<<gC, 256, 0, stream>>>(Kcb, Abf, vt, o_vp, o_nk, B);
  dim3 gD((V_NUM + 255) / 256, B / 8);
  k_skin<<<gD, 256, 0, stream>>>(o_nk, wgt, Grel, trans, o_verts, B);
}

// Round 3
// 190.329 us; speedup vs baseline: 2.2653x; 1.4148x over previous
//
#include <hip/hip_runtime.h>
#include <math.h>

#define V_NUM 6890
#define NJ 24
#define KTOT 217            // 10 betas + 207 pose_map
#define KP 256              // padded K (multiple of 64)
#define M_DIM (V_NUM * 3)   // 20670
#define MPAD 20736          // 162 * 128

typedef __attribute__((ext_vector_type(8))) short bf16x8;
typedef __attribute__((ext_vector_type(4))) float f32x4;

__constant__ int c_parents[NJ] = {-1,0,0,0,1,2,3,4,5,6,7,8,9,9,9,12,13,14,16,17,18,19,20,21};

__device__ __forceinline__ unsigned short f2bf(float x) {
  union { float f; unsigned int u; } v; v.f = x;
  unsigned int r = v.u + 0x7fffu + ((v.u >> 16) & 1u);
  return (unsigned short)(r >> 16);
}

#define GLOBAL_AS __attribute__((address_space(1)))
#define LDS_AS __attribute__((address_space(3)))
__device__ __forceinline__ void gl_lds16(const void* g, void* l) {
  __builtin_amdgcn_global_load_lds((const GLOBAL_AS unsigned int*)g,
                                   (LDS_AS unsigned int*)l, 16, 0, 0);
}

// ---------------- Kernel A: fold J_regressor into shapedirs/template ----------------
__global__ __launch_bounds__(256) void k_regress(
    const float* __restrict__ JR, const float* __restrict__ SD,
    const float* __restrict__ VT, float* __restrict__ JS, float* __restrict__ Jt) {
  int j = blockIdx.x;
  int tid = threadIdx.x;
  float part[33];
#pragma unroll
  for (int q = 0; q < 33; q++) part[q] = 0.f;
  for (int v = tid; v < V_NUM; v += 256) {
    float jr = JR[j * V_NUM + v];
#pragma unroll
    for (int cc = 0; cc < 3; cc++) {
      part[30 + cc] += jr * VT[v * 3 + cc];
#pragma unroll
      for (int ss = 0; ss < 10; ss++)
        part[cc * 10 + ss] += jr * SD[(v * 3 + cc) * 10 + ss];
    }
  }
  __shared__ float sm[33][4];
  int lane = tid & 63, wid = tid >> 6;
#pragma unroll
  for (int q = 0; q < 33; q++) {
    float x = part[q];
    for (int off = 32; off > 0; off >>= 1) x += __shfl_down(x, off);
    if (lane == 0) sm[q][wid] = x;
  }
  __syncthreads();
  if (tid < 33) {
    float s = sm[tid][0] + sm[tid][1] + sm[tid][2] + sm[tid][3];
    if (tid < 30) JS[j * 30 + tid] = s;
    else Jt[j * 3 + (tid - 30)] = s;
  }
}

// ---------------- Kernel A2: convert A = [shapedirs | posedirs] -> bf16 [MPAD][KP] ----------------
__global__ __launch_bounds__(256) void k_convA(
    const float* __restrict__ SD, const float* __restrict__ PD,
    unsigned short* __restrict__ Abf) {
  int m = blockIdx.x;
  int k = threadIdx.x;
  float v = 0.f;
  if (m < M_DIM && k < KTOT)
    v = (k < 10) ? SD[(size_t)m * 10 + k] : PD[(size_t)m * 207 + (k - 10)];
  Abf[(size_t)m * KP + k] = f2bf(v);
}

// ---------------- Kernel B: per-batch rodrigues + joints + kinematic chain ----------------
// Writes: Kcb [B][KP] bf16, GrelP [B][16][40] bf16 (GrelT: row c=p*4+q, col j; zero-pad),
//         outG [B][24][16], outJtr [B][24][3]
__global__ __launch_bounds__(64) void k_batch(
    const float* __restrict__ pose, const float* __restrict__ betas,
    const float* __restrict__ trans, const float* __restrict__ JS,
    const float* __restrict__ Jt, unsigned short* __restrict__ Kcb,
    unsigned short* __restrict__ GrelP, float* __restrict__ outG,
    float* __restrict__ outJtr, int B) {
  int b = blockIdx.x;
  int lane = threadIdx.x;
  __shared__ float rotS[NJ][9];
  __shared__ float jS[NJ * 3];
  __shared__ float Gs[NJ][12];
  __shared__ float GrS[NJ][12];

  if (lane < NJ) {
    float rx = pose[b * 72 + lane * 3 + 0];
    float ry = pose[b * 72 + lane * 3 + 1];
    float rz = pose[b * 72 + lane * 3 + 2];
    float a2 = rx * rx + ry * ry + rz * rz + 1e-16f;
    float ang = sqrtf(a2);
    float inv = 1.f / ang;
    float ux = rx * inv, uy = ry * inv, uz = rz * inv;
    float c = cosf(ang), s = sinf(ang), ic = 1.f - c;
    float R[9];
    R[0] = c + ic * ux * ux;      R[1] = ic * ux * uy - s * uz; R[2] = ic * ux * uz + s * uy;
    R[3] = ic * uy * ux + s * uz; R[4] = c + ic * uy * uy;      R[5] = ic * uy * uz - s * ux;
    R[6] = ic * uz * ux - s * uy; R[7] = ic * uz * uy + s * ux; R[8] = c + ic * uz * uz;
#pragma unroll
    for (int k = 0; k < 9; k++) rotS[lane][k] = R[k];
    if (lane > 0) {
#pragma unroll
      for (int k = 0; k < 9; k++) {
        float iden = (k == 0 || k == 4 || k == 8) ? 1.f : 0.f;
        Kcb[(size_t)b * KP + 10 + (lane - 1) * 9 + k] = f2bf(R[k] - iden);
      }
    }
  }
  if (lane < 10) Kcb[(size_t)b * KP + lane] = f2bf(betas[b * 10 + lane]);
  if (lane < KP - KTOT) Kcb[(size_t)b * KP + KTOT + lane] = 0;

  __syncthreads();
  for (int idx = lane; idx < 72; idx += 64) {
    float s = Jt[idx];
#pragma unroll
    for (int ss = 0; ss < 10; ss++) s += JS[idx * 10 + ss] * betas[b * 10 + ss];
    jS[idx] = s;
  }
  __syncthreads();

  if (lane == 0) {
#pragma unroll
    for (int p = 0; p < 3; p++) {
      Gs[0][p * 4 + 0] = rotS[0][p * 3 + 0];
      Gs[0][p * 4 + 1] = rotS[0][p * 3 + 1];
      Gs[0][p * 4 + 2] = rotS[0][p * 3 + 2];
      Gs[0][p * 4 + 3] = jS[p];
    }
    for (int i = 1; i < NJ; i++) {
      int par = c_parents[i];
      float t0 = jS[i * 3 + 0] - jS[par * 3 + 0];
      float t1 = jS[i * 3 + 1] - jS[par * 3 + 1];
      float t2 = jS[i * 3 + 2] - jS[par * 3 + 2];
#pragma unroll
      for (int p = 0; p < 3; p++) {
        float rp0 = Gs[par][p * 4 + 0], rp1 = Gs[par][p * 4 + 1], rp2 = Gs[par][p * 4 + 2];
#pragma unroll
        for (int q = 0; q < 3; q++) {
          Gs[i][p * 4 + q] = rp0 * rotS[i][0 * 3 + q] + rp1 * rotS[i][1 * 3 + q] + rp2 * rotS[i][2 * 3 + q];
        }
        Gs[i][p * 4 + 3] = rp0 * t0 + rp1 * t1 + rp2 * t2 + Gs[par][p * 4 + 3];
      }
    }
    for (int i = 0; i < NJ; i++) {
      float jx = jS[i * 3 + 0], jy = jS[i * 3 + 1], jz = jS[i * 3 + 2];
#pragma unroll
      for (int p = 0; p < 3; p++) {
        float g0 = Gs[i][p * 4 + 0], g1 = Gs[i][p * 4 + 1], g2 = Gs[i][p * 4 + 2];
        GrS[i][p * 4 + 0] = g0;
        GrS[i][p * 4 + 1] = g1;
        GrS[i][p * 4 + 2] = g2;
        GrS[i][p * 4 + 3] = Gs[i][p * 4 + 3] - (g0 * jx + g1 * jy + g2 * jz);
      }
    }
  }
  __syncthreads();

  for (int idx = lane; idx < NJ * 16; idx += 64) {
    int jj = idx >> 4, rc = idx & 15, p = rc >> 2, q = rc & 3;
    float val = (p < 3) ? Gs[jj][p * 4 + q] : ((q == 3) ? 1.f : 0.f);
    outG[(size_t)b * NJ * 16 + idx] = val;
  }
  for (int idx = lane; idx < NJ * 3; idx += 64) {
    int jj = idx / 3, p = idx % 3;
    outJtr[(size_t)b * NJ * 3 + idx] = Gs[jj][p * 4 + 3] + trans[b * 3 + p];
  }
  // GrelT bf16 panel: [c=0..15][j=0..39], zeros outside c<12, j<24
  for (int idx = lane; idx < 16 * 40; idx += 64) {
    int c = idx / 40, j = idx % 40;
    GrelP[(size_t)b * 640 + idx] = (c < 12 && j < NJ) ? f2bf(GrS[j][c]) : (unsigned short)0;
  }
}

// ---------------- Kernel C: MFMA GEMM  D[b][m] = sum_k Kcb[b][k] * Abf[m][k] + VT[m] ----------------
__global__ __launch_bounds__(256) void k_pose_mfma(
    const unsigned short* __restrict__ Kcb, const unsigned short* __restrict__ Abf,
    const float* __restrict__ VT,
    float* __restrict__ outVP, float* __restrict__ outNK, int B) {
  __shared__ unsigned short At[128 * 64];
  __shared__ unsigned short Bt[128 * 64];
  const int tid = threadIdx.x;
  const int lane = tid & 63;
  const int w = tid >> 6;
  const int wr = w >> 1, wc = w & 1;
  const int b0 = blockIdx.y * 128;
  const int m0 = blockIdx.x * 128;

  f32x4 acc[4][4];
#pragma unroll
  for (int i = 0; i < 4; i++)
#pragma unroll
    for (int j = 0; j < 4; j++) acc[i][j] = (f32x4){0.f, 0.f, 0.f, 0.f};

  int Lrow[4], Lkb[4];
#pragma unroll
  for (int i = 0; i < 4; i++) {
    int L = w * 4096 + i * 1024 + lane * 16;
    int row = L >> 7;
    int kb = (L & 127) ^ ((row & 7) << 4);
    Lrow[i] = row;
    Lkb[i] = kb >> 1;
  }

  for (int kt = 0; kt < KP / 64; ++kt) {
#pragma unroll
    for (int i = 0; i < 4; i++) {
      const unsigned short* gA = Kcb + (size_t)(b0 + Lrow[i]) * KP + kt * 64 + Lkb[i];
      gl_lds16(gA, (char*)At + w * 4096 + i * 1024);
    }
#pragma unroll
    for (int i = 0; i < 4; i++) {
      const unsigned short* gB = Abf + (size_t)(m0 + Lrow[i]) * KP + kt * 64 + Lkb[i];
      gl_lds16(gB, (char*)Bt + w * 4096 + i * 1024);
    }
    __syncthreads();

#pragma unroll
    for (int h = 0; h < 2; ++h) {
      bf16x8 af[4], bfr[4];
#pragma unroll
      for (int fi = 0; fi < 4; fi++) {
        int row = wr * 64 + fi * 16 + (lane & 15);
        int byte = (row << 7) + ((h * 64 + ((lane >> 4) << 4)) ^ ((row & 7) << 4));
        af[fi] = *(const bf16x8*)((const char*)At + byte);
      }
#pragma unroll
      for (int fj = 0; fj < 4; fj++) {
        int row = wc * 64 + fj * 16 + (lane & 15);
        int byte = (row << 7) + ((h * 64 + ((lane >> 4) << 4)) ^ ((row & 7) << 4));
        bfr[fj] = *(const bf16x8*)((const char*)Bt + byte);
      }
#pragma unroll
      for (int fi = 0; fi < 4; fi++)
#pragma unroll
        for (int fj = 0; fj < 4; fj++)
          acc[fi][fj] = __builtin_amdgcn_mfma_f32_16x16x32_bf16(af[fi], bfr[fj], acc[fi][fj], 0, 0, 0);
    }
    __syncthreads();
  }

#pragma unroll
  for (int fj = 0; fj < 4; fj++) {
    int cm = m0 + wc * 64 + fj * 16 + (lane & 15);
    if (cm >= M_DIM) continue;
    float vt = VT[cm];
#pragma unroll
    for (int fi = 0; fi < 4; fi++) {
      int rb = b0 + wr * 64 + fi * 16 + ((lane >> 4) << 2);
#pragma unroll
      for (int r = 0; r < 4; r++) {
        float val = acc[fi][fj][r] + vt;
        size_t o = (size_t)(rb + r) * M_DIM + cm;
        outVP[o] = val;
        outNK[o] = val;
      }
    }
  }
}

// ---------------- Kernel D: MFMA skinning ----------------
// Per block: 256 verts x 16 batches. T[c][v] = sum_j GrelT[c][j] * W[v][j] via one
// mfma_f32_16x16x32_bf16 per 16-vert subtile; lane then holds T[v][4p..4p+3] = row p
// of the vert's 3x4 transform -> apply to (x,1) directly, no transpose.
__global__ __launch_bounds__(256) void k_skin_mfma(
    const float* __restrict__ NK, const float* __restrict__ W,
    const unsigned short* __restrict__ GrelP, const float* __restrict__ trans,
    float* __restrict__ outVerts, int B) {
  __shared__ unsigned short gsh[16 * 40];   // GrelT panel, 1280 B
  __shared__ float xsh[256 * 3];
  __shared__ float tsh[4];
  const int tid = threadIdx.x;
  const int lane = tid & 63;
  const int w = tid >> 6;
  const int v0 = blockIdx.x * 256;
  const int b0 = blockIdx.y * 16;
  const int kb = (lane >> 4) * 8;   // k-base of this lane's fragment
  const int p = lane >> 4;          // output row (3 = idle)
  const int vl16 = lane & 15;

  // W B-fragments: one per 16-vert subtile, reused across all 16 batches.
  bf16x8 wfrag[4];
#pragma unroll
  for (int sub = 0; sub < 4; sub++) {
    int v = v0 + w * 64 + sub * 16 + vl16;
    bf16x8 f;
    if (kb < NJ && v < V_NUM) {
      const float* wp = W + (size_t)v * NJ + kb;
#pragma unroll
      for (int e = 0; e < 8; e++) f[e] = (short)f2bf(wp[e]);
    } else {
#pragma unroll
      for (int e = 0; e < 8; e++) f[e] = 0;
    }
    wfrag[sub] = f;
  }

  for (int bi = 0; bi < 16; bi++) {
    int b = b0 + bi;
    __syncthreads();
    // stage GrelT panel (320 dwords) + naked tile (768 floats) + trans
    const unsigned int* gsrc = (const unsigned int*)(GrelP + (size_t)b * 640);
    for (int i = tid; i < 320; i += 256) ((unsigned int*)gsh)[i] = gsrc[i];
    const float* nkb = NK + (size_t)b * M_DIM;
    int base3 = v0 * 3;
    for (int i = tid; i < 768; i += 256)
      xsh[i] = (base3 + i < M_DIM) ? nkb[base3 + i] : 0.f;
    if (tid < 3) tsh[tid] = trans[b * 3 + tid];
    __syncthreads();

    // A-fragment: GrelT[c = lane&15][kb..kb+7], contiguous in gsh row (pad 40)
    bf16x8 af = *(const bf16x8*)&gsh[vl16 * 40 + kb];

#pragma unroll
    for (int sub = 0; sub < 4; sub++) {
      f32x4 acc = (f32x4){0.f, 0.f, 0.f, 0.f};
      acc = __builtin_amdgcn_mfma_f32_16x16x32_bf16(af, wfrag[sub], acc, 0, 0, 0);
      if (p < 3) {
        int vloc = w * 64 + sub * 16 + vl16;
        float x0 = xsh[vloc * 3 + 0], x1 = xsh[vloc * 3 + 1], x2 = xsh[vloc * 3 + 2];
        float outv = acc[0] * x0 + acc[1] * x1 + acc[2] * x2 + acc[3] + tsh[p];
        int vg = v0 + vloc;
        if (vg < V_NUM)
          outVerts[(size_t)b * M_DIM + (size_t)vg * 3 + p] = outv;
      }
    }
  }
}

extern "C" void kernel_launch(void* const* d_in, const int* in_sizes, int n_in,
                              void* d_out, int out_size, void* d_ws, size_t ws_size,
                              hipStream_t stream) {
  const float* pose  = (const float*)d_in[0];
  const float* betas = (const float*)d_in[1];
  const float* trans = (const float*)d_in[2];
  const float* vt    = (const float*)d_in[3];
  const float* sd    = (const float*)d_in[4];
  const float* pd    = (const float*)d_in[5];
  const float* jreg  = (const float*)d_in[6];
  const float* wgt   = (const float*)d_in[7];
  int B = in_sizes[0] / 72;

  float* out = (float*)d_out;
  size_t nvb = (size_t)B * M_DIM;
  float* o_verts = out;
  float* o_jtr   = o_verts + nvb;
  float* o_vp    = o_jtr + (size_t)B * NJ * 3;
  float* o_nk    = o_vp + nvb;
  float* o_G     = o_nk + nvb;

  char* wsb = (char*)d_ws;
  float* JS = (float*)wsb;                          // 720 f32
  float* Jt = JS + 720;                             // 72 f32
  size_t off = (720 + 72) * 4;                      // 3168 B (16-aligned)
  unsigned short* Kcb   = (unsigned short*)(wsb + off);                       // B*KP
  unsigned short* Abf   = (unsigned short*)(wsb + off + (size_t)B * KP * 2);  // MPAD*KP
  unsigned short* GrelP = Abf + (size_t)MPAD * KP;                            // B*640

  k_regress<<<24, 256, 0, stream>>>(jreg, sd, vt, JS, Jt);
  k_convA<<<MPAD, 256, 0, stream>>>(sd, pd, Abf);
  k_batch<<<B, 64, 0, stream>>>(pose, betas, trans, JS, Jt, Kcb, GrelP, o_G, o_jtr, B);
  dim3 gC(MPAD / 128, B / 128);
  k_pose_mfma<<<gC, 256, 0, stream>>>(Kcb, Abf, vt, o_vp, o_nk, B);
  dim3 gD((V_NUM + 255) / 256, B / 16);
  k_skin_mfma<<<gD, 256, 0, stream>>>(o_nk, wgt, GrelP, trans, o_verts, B);
}